// Round 4
// baseline (268.325 us; speedup 1.0000x reference)
//
#include <hip/hip_runtime.h>
#include <hip/hip_bf16.h>
#include <math.h>

// AGTBlock: x->MLP->h; Q,K,V=h@W*; edge attention grouped by dst with segment
// softmax; msg = attn*(V[src]+posMLP(pos[src]-pos[dst])); out = LN(LN(sum+h)+x).
// Key restructure: posMLP second layer (@Wp2) is linear -> pull it out of the
// edge sum; accumulate pre-Wp2 relu activations per dst node, single node GEMM.

#define NN 10000
#define NE 320000
#define DD 256

typedef __bf16 bf16;
typedef __bf16 bf16x8 __attribute__((ext_vector_type(8)));
typedef __bf16 bf16x4 __attribute__((ext_vector_type(4)));
typedef float f32x4 __attribute__((ext_vector_type(4)));

__device__ __forceinline__ float wave_sum(float v) {
#pragma unroll
  for (int off = 32; off; off >>= 1) v += __shfl_xor(v, off, 64);
  return v;
}
__device__ __forceinline__ float wave_max(float v) {
#pragma unroll
  for (int off = 32; off; off >>= 1) v = fmaxf(v, __shfl_xor(v, off, 64));
  return v;
}

// ---------------- edge dtype detect (int32 vs int64) ----------------
__global__ void detect_kernel(const int* __restrict__ ei, int* __restrict__ flag) {
  if (threadIdx.x == 0) {
    int is64 = 1;
    for (int i = 0; i < 256; ++i)
      if (ei[2 * i + 1] != 0) { is64 = 0; break; }
    *flag = is64;
  }
}

__device__ __forceinline__ void load_edge(const int* __restrict__ ei, int is64,
                                          int e, int& s, int& dn) {
  if (is64) {
    const long long* e64 = (const long long*)ei;
    s = (int)e64[e];
    dn = (int)e64[NE + e];
  } else {
    s = ei[e];
    dn = ei[NE + e];
  }
  // defensive clamp: malformed indices must not fault or hang the GPU
  s = min(max(s, 0), NN - 1);
  dn = min(max(dn, 0), NN - 1);
}

// ---------------- prep: weight transpose->bf16, x->bf16 ----------------
struct TW { const float* w[6]; bf16* o[6]; };

__global__ __launch_bounds__(256) void transpose_all(TW tw) {
  int b = blockIdx.x >> 8;
  int idx = ((blockIdx.x & 255) << 8) | threadIdx.x;  // 0..65535
  int nn = idx >> 8, k = idx & 255;
  tw.o[b][idx] = (bf16)tw.w[b][k * 256 + nn];         // Bt[n][k] = W[k][n]
}

__global__ __launch_bounds__(256) void cvt_bf16(const float* __restrict__ x,
                                                bf16* __restrict__ o, int n) {
  int i = (blockIdx.x * 256 + threadIdx.x) * 4;
  if (i + 3 < n) {
    float4 v = *(const float4*)(x + i);
    bf16x4 b;
    b[0] = (bf16)v.x; b[1] = (bf16)v.y; b[2] = (bf16)v.z; b[3] = (bf16)v.w;
    *(bf16x4*)(o + i) = b;
  }
}

// ---------------- GEMM: C[M,256] = A[M,256] @ Bt^T + bias ----------------
// A row-major [M][K=256] bf16, Bt row-major [N=256][K=256] bf16 (pre-transposed W).
// Direct-from-global MFMA fragments (matrices tiny; L1/L2 resident). Each wave:
// 16 rows x 64 cols via 4 accumulators of 16x16, K-loop of 8 x 32.
template <int RELU, int WF, int WB>
__global__ __launch_bounds__(256) void gemm256(
    const bf16* __restrict__ A, const bf16* __restrict__ Bt,
    const float* __restrict__ bias, float* __restrict__ Cf,
    bf16* __restrict__ Cb, int M) {
  int w = threadIdx.x >> 6, lane = threadIdx.x & 63;
  int lr = lane & 15, kh = lane >> 4;               // kh in 0..3
  int row16 = (blockIdx.x * 4 + w) * 16;
  int colbase = blockIdx.y * 64;
  f32x4 acc[4] = {};
  int arow = row16 + lr;
  if (arow >= M) arow = M - 1;                      // clamp; outputs masked
  const bf16* Ap = A + arow * 256 + kh * 8;
  const bf16* Bp0 = Bt + (colbase + lr) * 256 + kh * 8;
#pragma unroll
  for (int kk = 0; kk < 8; ++kk) {
    bf16x8 af = *(const bf16x8*)(Ap + kk * 32);
#pragma unroll
    for (int nf = 0; nf < 4; ++nf) {
      bf16x8 bfrag = *(const bf16x8*)(Bp0 + nf * 16 * 256 + kk * 32);
      acc[nf] = __builtin_amdgcn_mfma_f32_16x16x32_bf16(af, bfrag, acc[nf], 0, 0, 0);
    }
  }
  // C/D layout (m89-verified): col = lane&15, row = (lane>>4)*4 + j
  int crow = row16 + kh * 4;
#pragma unroll
  for (int nf = 0; nf < 4; ++nf) {
    int ccol = colbase + nf * 16 + lr;
    float bv = bias ? bias[ccol] : 0.0f;
#pragma unroll
    for (int j = 0; j < 4; ++j) {
      int r = crow + j;
      if (r < M) {
        float v = acc[nf][j] + bv;
        if (RELU) v = fmaxf(v, 0.0f);
        if (WF) Cf[r * 256 + ccol] = v;
        if (WB) Cb[r * 256 + ccol] = (bf16)v;
      }
    }
  }
}

// ---------------- CSR build by dst ----------------
__global__ void zero_int(int* __restrict__ p, int n) {
  int i = blockIdx.x * 256 + threadIdx.x;
  if (i < n) p[i] = 0;
}

__global__ void hist_kernel(const int* __restrict__ ei, const int* __restrict__ flag,
                            int* __restrict__ deg) {
  int e = blockIdx.x * 256 + threadIdx.x;
  if (e < NE) {
    int s, dn;
    load_edge(ei, *flag, e, s, dn);
    atomicAdd(&deg[dn], 1);
  }
}

__global__ __launch_bounds__(1024) void scan_kernel(
    const int* __restrict__ deg, int* __restrict__ rowptr,
    int* __restrict__ cursor, int n) {
  __shared__ int buf[1024];
  __shared__ int carry_s;
  int t = threadIdx.x;
  if (t == 0) { carry_s = 0; rowptr[0] = 0; }
  __syncthreads();
  for (int base = 0; base < n; base += 1024) {
    int v = (base + t < n) ? deg[base + t] : 0;
    int x = v;
    buf[t] = x;
    __syncthreads();
    for (int off = 1; off < 1024; off <<= 1) {
      int y = (t >= off) ? buf[t - off] : 0;
      __syncthreads();
      x += y;
      buf[t] = x;
      __syncthreads();
    }
    int carry = carry_s;
    if (base + t < n) {
      rowptr[base + t + 1] = carry + x;
      cursor[base + t] = carry + x - v;   // exclusive prefix = segment start
    }
    __syncthreads();
    if (t == 1023) carry_s = carry + buf[1023];
    __syncthreads();
  }
}

__global__ void scatter_kernel(const int* __restrict__ ei, const int* __restrict__ flag,
                               int* __restrict__ cursor, int* __restrict__ srcs) {
  int e = blockIdx.x * 256 + threadIdx.x;
  if (e < NE) {
    int s, dn;
    load_edge(ei, *flag, e, s, dn);
    int slot = atomicAdd(&cursor[dn], 1);
    if (slot >= 0 && slot < NE) srcs[slot] = s;
  }
}

// ---------------- per-dst attention (1 wave / node) ----------------
#define CAP 256
__global__ __launch_bounds__(64) void attn_kernel(
    const bf16* __restrict__ Qb, const bf16* __restrict__ Kb, const bf16* __restrict__ Vb,
    const float* __restrict__ pos, const float* __restrict__ Wp1, const float* __restrict__ bp1,
    const int* __restrict__ rowptr, const int* __restrict__ srcs,
    float* __restrict__ acc1, bf16* __restrict__ acc2, float* __restrict__ sattn) {
  int n = blockIdx.x, lane = threadIdx.x;
  int d = lane * 4;
  __shared__ float s_alpha[CAP];
  __shared__ int s_src[CAP];
  // defensive: rowptr is kernel-computed; clamp so no state can hang the loop
  int e0 = min(max(rowptr[n], 0), NE);
  int e1 = min(max(rowptr[n + 1], e0), NE);
  float q[4];
  {
    bf16x4 qv = *(const bf16x4*)(Qb + n * 256 + d);
    q[0] = (float)qv[0]; q[1] = (float)qv[1]; q[2] = (float)qv[2]; q[3] = (float)qv[3];
  }
  float px = pos[n * 3], py = pos[n * 3 + 1], pz = pos[n * 3 + 2];
  float w0[4], w1[4], w2[4], bp[4];
#pragma unroll
  for (int j = 0; j < 4; ++j) {
    w0[j] = Wp1[d + j];
    w1[j] = Wp1[256 + d + j];
    w2[j] = Wp1[512 + d + j];
    bp[j] = bp1[d + j];
  }
  float m = -INFINITY, denom = 0.0f;
  float aV[4] = {0, 0, 0, 0}, aP[4] = {0, 0, 0, 0};
  for (int base = e0; base < e1; base += CAP) {
    int csz = min(CAP, e1 - base);
    for (int i = lane; i < csz; i += 64) s_src[i] = srcs[base + i];
    __syncthreads();
    // pass 1: alpha_e = dot(Q[n], K[src]) / 16, whole wave per edge
    for (int i = 0; i < csz; ++i) {
      int s = s_src[i];
      bf16x4 kv = *(const bf16x4*)(Kb + s * 256 + d);
      float p = q[0] * (float)kv[0] + q[1] * (float)kv[1] +
                q[2] * (float)kv[2] + q[3] * (float)kv[3];
      p = wave_sum(p);
      if (lane == 0) s_alpha[i] = p * (1.0f / 16.0f);
    }
    __syncthreads();
    // online softmax rescale for this chunk
    float mc = -INFINITY;
    for (int i = lane; i < csz; i += 64) mc = fmaxf(mc, s_alpha[i]);
    mc = wave_max(mc);
    float newm = fmaxf(m, mc);
    float scale = expf(m - newm);  // 0 on first chunk (m=-inf), 1 if unchanged
    denom *= scale;
#pragma unroll
    for (int j = 0; j < 4; ++j) { aV[j] *= scale; aP[j] *= scale; }
    m = newm;
    // pass 2: accumulate w*(V[src]) and w*relu(rel_pos@Wp1+bp1)
    for (int i = 0; i < csz; ++i) {
      float wgt = expf(s_alpha[i] - m);
      denom += wgt;  // uniform across lanes
      int s = s_src[i];
      bf16x4 vv = *(const bf16x4*)(Vb + s * 256 + d);
      float rx = pos[s * 3] - px, ry = pos[s * 3 + 1] - py, rz = pos[s * 3 + 2] - pz;
#pragma unroll
      for (int j = 0; j < 4; ++j) {
        float p1 = fmaf(rx, w0[j], fmaf(ry, w1[j], fmaf(rz, w2[j], bp[j])));
        p1 = fmaxf(p1, 0.0f);
        aV[j] = fmaf(wgt, (float)vv[j], aV[j]);
        aP[j] = fmaf(wgt, p1, aP[j]);
      }
    }
    __syncthreads();
  }
  float r = 1.0f / (denom + 1e-16f);
  if (lane == 0) sattn[n] = denom * r;
#pragma unroll
  for (int j = 0; j < 4; ++j) {
    acc1[n * 256 + d + j] = aV[j] * r;
    acc2[n * 256 + d + j] = (bf16)(aP[j] * r);
  }
}

// ---------------- fused epilogue: residuals + two LayerNorms ----------------
__global__ __launch_bounds__(64) void final_kernel(
    const float* __restrict__ acc1, const float* __restrict__ tmp,
    const float* __restrict__ sattn, const float* __restrict__ bp2,
    const float* __restrict__ hf, const float* __restrict__ x,
    const float* __restrict__ g1, const float* __restrict__ b1n,
    const float* __restrict__ g2, const float* __restrict__ b2n,
    float* __restrict__ out) {
  int n = blockIdx.x, lane = threadIdx.x, d = lane * 4, nd = n * 256 + d;
  float s = sattn[n];
  float v[4];
#pragma unroll
  for (int j = 0; j < 4; ++j)
    v[j] = acc1[nd + j] + tmp[nd + j] + s * bp2[d + j] + hf[nd + j];
  float mu = wave_sum(v[0] + v[1] + v[2] + v[3]) * (1.0f / 256.0f);
  float ss = 0;
#pragma unroll
  for (int j = 0; j < 4; ++j) { float t = v[j] - mu; ss += t * t; }
  float rstd = rsqrtf(wave_sum(ss) * (1.0f / 256.0f) + 1e-5f);
  float u[4];
#pragma unroll
  for (int j = 0; j < 4; ++j)
    u[j] = (v[j] - mu) * rstd * g1[d + j] + b1n[d + j] + x[nd + j];
  float mu2 = wave_sum(u[0] + u[1] + u[2] + u[3]) * (1.0f / 256.0f);
  float ss2 = 0;
#pragma unroll
  for (int j = 0; j < 4; ++j) { float t = u[j] - mu2; ss2 += t * t; }
  float rstd2 = rsqrtf(wave_sum(ss2) * (1.0f / 256.0f) + 1e-5f);
#pragma unroll
  for (int j = 0; j < 4; ++j)
    out[nd + j] = (u[j] - mu2) * rstd2 * g2[d + j] + b2n[d + j];
}

extern "C" void kernel_launch(void* const* d_in, const int* in_sizes, int n_in,
                              void* d_out, int out_size, void* d_ws, size_t ws_size,
                              hipStream_t stream) {
  (void)in_sizes; (void)n_in; (void)out_size; (void)ws_size;
  const float* x   = (const float*)d_in[0];
  const int*   ei  = (const int*)d_in[1];
  const float* pos = (const float*)d_in[2];
  const float* Wm1 = (const float*)d_in[3];
  const float* bm1 = (const float*)d_in[4];
  const float* Wm2 = (const float*)d_in[5];
  const float* bm2 = (const float*)d_in[6];
  const float* Wq  = (const float*)d_in[7];
  const float* bq  = (const float*)d_in[8];
  const float* Wk  = (const float*)d_in[9];
  const float* bk  = (const float*)d_in[10];
  const float* Wv  = (const float*)d_in[11];
  const float* bv  = (const float*)d_in[12];
  const float* Wp1 = (const float*)d_in[13];
  const float* bp1 = (const float*)d_in[14];
  const float* Wp2 = (const float*)d_in[15];
  const float* bp2 = (const float*)d_in[16];
  const float* g1  = (const float*)d_in[17];
  const float* b1n = (const float*)d_in[18];
  const float* g2  = (const float*)d_in[19];
  const float* b2n = (const float*)d_in[20];

  const size_t ND = (size_t)NN * DD;
  char* p = (char*)d_ws;
  auto alloc = [&](size_t bytes) {
    char* r = p;
    p += (bytes + 255) & ~(size_t)255;
    return r;
  };
  bf16* bt[6];
  for (int i = 0; i < 6; ++i) bt[i] = (bf16*)alloc(256 * 256 * sizeof(bf16));
  bf16* xb   = (bf16*)alloc(ND * 2);
  bf16* h1b  = (bf16*)alloc(ND * 2);
  bf16* hb   = (bf16*)alloc(ND * 2);
  float* hf  = (float*)alloc(ND * 4);
  bf16* Qb   = (bf16*)alloc(ND * 2);
  float* acc1 = (float*)alloc(ND * 4);
  bf16* acc2  = (bf16*)alloc(ND * 2);
  float* tmp  = (float*)alloc(ND * 4);
  float* sattn = (float*)alloc(NN * 4);
  int* deg    = (int*)alloc(NN * 4);
  int* rowptr = (int*)alloc((NN + 1) * 4);
  int* cursor = (int*)alloc(NN * 4);
  int* srcs   = (int*)alloc(NE * 4);
  int* eflag  = (int*)alloc(256);
  // safe aliases (xb dead after G1, h1b dead after G2)
  bf16* Kb = xb;
  bf16* Vb = h1b;

  detect_kernel<<<1, 64, 0, stream>>>(ei, eflag);
  zero_int<<<(NN + 255) / 256, 256, 0, stream>>>(deg, NN);

  TW tw;
  tw.w[0] = Wm1; tw.w[1] = Wm2; tw.w[2] = Wq; tw.w[3] = Wk; tw.w[4] = Wv; tw.w[5] = Wp2;
  for (int i = 0; i < 6; ++i) tw.o[i] = bt[i];
  transpose_all<<<6 * 256, 256, 0, stream>>>(tw);
  cvt_bf16<<<(int)(ND / 1024), 256, 0, stream>>>(x, xb, (int)ND);

  dim3 ggrid((NN + 63) / 64, 4);
  // h1 = relu(x@Wm1+bm1); h = h1@Wm2+bm2 (f32 + bf16); Q,K,V
  gemm256<1, 0, 1><<<ggrid, 256, 0, stream>>>(xb, bt[0], bm1, nullptr, h1b, NN);
  gemm256<0, 1, 1><<<ggrid, 256, 0, stream>>>(h1b, bt[1], bm2, hf, hb, NN);
  gemm256<0, 0, 1><<<ggrid, 256, 0, stream>>>(hb, bt[2], bq, nullptr, Qb, NN);
  gemm256<0, 0, 1><<<ggrid, 256, 0, stream>>>(hb, bt[3], bk, nullptr, Kb, NN);
  gemm256<0, 0, 1><<<ggrid, 256, 0, stream>>>(hb, bt[4], bv, nullptr, Vb, NN);

  hist_kernel<<<(NE + 255) / 256, 256, 0, stream>>>(ei, eflag, deg);
  scan_kernel<<<1, 1024, 0, stream>>>(deg, rowptr, cursor, NN);
  scatter_kernel<<<(NE + 255) / 256, 256, 0, stream>>>(ei, eflag, cursor, srcs);

  attn_kernel<<<NN, 64, 0, stream>>>(Qb, Kb, Vb, pos, Wp1, bp1, rowptr, srcs,
                                     acc1, acc2, sattn);
  // tmp = (normalized accP) @ Wp2
  gemm256<0, 1, 0><<<ggrid, 256, 0, stream>>>(acc2, bt[5], nullptr, tmp, nullptr, NN);

  final_kernel<<<NN, 64, 0, stream>>>(acc1, tmp, sattn, bp2, hf, x, g1, b1n, g2,
                                      b2n, (float*)d_out);
}

// Round 5
// 262.132 us; speedup vs baseline: 1.0236x; 1.0236x over previous
//
#include <hip/hip_runtime.h>
#include <hip/hip_bf16.h>
#include <math.h>

// AGTBlock: x->MLP->h; Q,K,V=h@W*; edge attention grouped by dst with segment
// softmax; msg = attn*(V[src]+posMLP(pos[src]-pos[dst])); out = LN(LN(sum+h)+x).
// Restructure: Wp2 is linear -> pulled out of the edge sum (node GEMM on the
// attn-weighted relu activations). Attn: 1 wave/node, 4 nodes/block, no LDS —
// src indices broadcast via readlane (SGPR row base -> coalesced row gathers).

#define NN 10000
#define NE 320000
#define DD 256

typedef __bf16 bf16;
typedef __bf16 bf16x8 __attribute__((ext_vector_type(8)));
typedef __bf16 bf16x4 __attribute__((ext_vector_type(4)));
typedef float f32x4 __attribute__((ext_vector_type(4)));

__device__ __forceinline__ float wave_sum(float v) {
#pragma unroll
  for (int off = 32; off; off >>= 1) v += __shfl_xor(v, off, 64);
  return v;
}
__device__ __forceinline__ float wave_max(float v) {
#pragma unroll
  for (int off = 32; off; off >>= 1) v = fmaxf(v, __shfl_xor(v, off, 64));
  return v;
}

// ---------------- edge dtype detect (int32 vs int64) ----------------
__global__ void detect_kernel(const int* __restrict__ ei, int* __restrict__ flag) {
  if (threadIdx.x == 0) {
    int is64 = 1;
    for (int i = 0; i < 256; ++i)
      if (ei[2 * i + 1] != 0) { is64 = 0; break; }
    *flag = is64;
  }
}

__device__ __forceinline__ void load_edge(const int* __restrict__ ei, int is64,
                                          int e, int& s, int& dn) {
  if (is64) {
    const long long* e64 = (const long long*)ei;
    s = (int)e64[e];
    dn = (int)e64[NE + e];
  } else {
    s = ei[e];
    dn = ei[NE + e];
  }
  s = min(max(s, 0), NN - 1);
  dn = min(max(dn, 0), NN - 1);
}

// ---------------- prep: tiled weight transpose -> bf16, x -> bf16 ----------------
struct TW { const float* w[6]; bf16* o[6]; };

// 32x32 LDS tile transpose, coalesced reads and writes. grid = 6 * 64 tiles.
__global__ __launch_bounds__(256) void transpose_all(TW tw) {
  int t = blockIdx.x & 63;   // tile within matrix (8x8 grid of 32x32)
  int b = blockIdx.x >> 6;   // matrix 0..5
  int tr = (t >> 3) * 32;    // k-tile base
  int tc = (t & 7) * 32;     // n-tile base
  __shared__ float tile[32][33];
  int tx = threadIdx.x & 31, ty = threadIdx.x >> 5;  // 32 x 8
  const float* w = tw.w[b];
#pragma unroll
  for (int i = 0; i < 32; i += 8)
    tile[ty + i][tx] = w[(tr + ty + i) * 256 + tc + tx];
  __syncthreads();
  bf16* o = tw.o[b];
#pragma unroll
  for (int i = 0; i < 32; i += 8)
    o[(tc + ty + i) * 256 + tr + tx] = (bf16)tile[tx][ty + i];  // o[n][k]=w[k][n]
}

__global__ __launch_bounds__(256) void cvt_bf16(const float* __restrict__ x,
                                                bf16* __restrict__ o, int n) {
  int i = (blockIdx.x * 256 + threadIdx.x) * 4;
  if (i + 3 < n) {
    float4 v = *(const float4*)(x + i);
    bf16x4 b;
    b[0] = (bf16)v.x; b[1] = (bf16)v.y; b[2] = (bf16)v.z; b[3] = (bf16)v.w;
    *(bf16x4*)(o + i) = b;
  }
}

// ---------------- GEMM: C[M,256] = A[M,256] @ Bt[seg]^T + bias[seg] ----------------
// Bt0 = concatenated pre-transposed weights, seg s at Bt0 + s*65536 ([256][256]).
// Wave: 16 rows x 128 cols (8 16x16 frags). grid = (ceil(M/64), 2*NSEG);
// y>>1 = segment, y&1 = column half. Direct-from-global fragments (B L2-hot).
struct GSeg { const float* bias; float* cf; bf16* cb; };
struct GArgs { GSeg s[3]; };

template <int RELU>
__global__ __launch_bounds__(256) void gemmw(
    const bf16* __restrict__ A, const bf16* __restrict__ Bt0, GArgs ga, int M) {
  int w = threadIdx.x >> 6, lane = threadIdx.x & 63;
  int lr = lane & 15, kh = lane >> 4;
  int row16 = (blockIdx.x * 4 + w) * 16;
  int seg = blockIdx.y >> 1;
  int colbase = (blockIdx.y & 1) * 128;
  GSeg gs = ga.s[seg];
  const bf16* Bt = Bt0 + seg * 65536;
  f32x4 acc[8] = {};
  int arow = row16 + lr;
  if (arow >= M) arow = M - 1;  // clamp; masked on store
  const bf16* Ap = A + (size_t)arow * 256 + kh * 8;
  const bf16* Bp = Bt + (size_t)(colbase + lr) * 256 + kh * 8;
#pragma unroll
  for (int kk = 0; kk < 8; ++kk) {
    bf16x8 af = *(const bf16x8*)(Ap + kk * 32);
#pragma unroll
    for (int nf = 0; nf < 8; ++nf) {
      bf16x8 bfr = *(const bf16x8*)(Bp + nf * 16 * 256 + kk * 32);
      acc[nf] = __builtin_amdgcn_mfma_f32_16x16x32_bf16(af, bfr, acc[nf], 0, 0, 0);
    }
  }
  // C/D layout (m89): col = lane&15, row = (lane>>4)*4 + j
  int crow = row16 + kh * 4;
#pragma unroll
  for (int nf = 0; nf < 8; ++nf) {
    int ccol = colbase + nf * 16 + lr;
    float bv = gs.bias ? gs.bias[ccol] : 0.0f;
#pragma unroll
    for (int j = 0; j < 4; ++j) {
      int r = crow + j;
      if (r < M) {
        float v = acc[nf][j] + bv;
        if (RELU) v = fmaxf(v, 0.0f);
        if (gs.cf) gs.cf[(size_t)r * 256 + ccol] = v;
        if (gs.cb) gs.cb[(size_t)r * 256 + ccol] = (bf16)v;
      }
    }
  }
}

// ---------------- CSR build by dst ----------------
__global__ void hist_kernel(const int* __restrict__ ei, const int* __restrict__ flag,
                            int* __restrict__ deg) {
  int e = blockIdx.x * 256 + threadIdx.x;
  if (e < NE) {
    int s, dn;
    load_edge(ei, *flag, e, s, dn);
    atomicAdd(&deg[dn], 1);
  }
}

// shuffle-based scan: 4 barriers per 1024-chunk (vs 20 for Hillis-Steele).
__global__ __launch_bounds__(1024) void scan_kernel(
    const int* __restrict__ deg, int* __restrict__ rowptr,
    int* __restrict__ cursor, int n) {
  __shared__ int wsum[16];
  __shared__ int carry_s;
  int t = threadIdx.x, wid = t >> 6, lane = t & 63;
  if (t == 0) { carry_s = 0; rowptr[0] = 0; }
  __syncthreads();
  for (int base = 0; base < n; base += 1024) {
    int idx = base + t;
    int v = (idx < n) ? deg[idx] : 0;
    int x = v;
#pragma unroll
    for (int off = 1; off < 64; off <<= 1) {
      int y = __shfl_up(x, off, 64);
      if (lane >= off) x += y;
    }
    if (lane == 63) wsum[wid] = x;
    __syncthreads();
    if (wid == 0) {
      int s = (lane < 16) ? wsum[lane] : 0;
#pragma unroll
      for (int off = 1; off < 16; off <<= 1) {
        int y = __shfl_up(s, off, 64);
        if (lane >= off) s += y;
      }
      if (lane < 16) wsum[lane] = s;
    }
    __syncthreads();
    int waveoff = (wid > 0) ? wsum[wid - 1] : 0;
    int carry = carry_s;
    int incl = carry + waveoff + x;
    if (idx < n) {
      rowptr[idx + 1] = incl;
      cursor[idx] = incl - v;  // exclusive prefix = segment start
    }
    __syncthreads();
    if (t == 1023) carry_s = incl;  // total through this chunk
    __syncthreads();
  }
}

__global__ void scatter_kernel(const int* __restrict__ ei, const int* __restrict__ flag,
                               int* __restrict__ cursor, int* __restrict__ srcs) {
  int e = blockIdx.x * 256 + threadIdx.x;
  if (e < NE) {
    int s, dn;
    load_edge(ei, *flag, e, s, dn);
    int slot = atomicAdd(&cursor[dn], 1);
    if (slot >= 0 && slot < NE) srcs[slot] = s;
  }
}

// ---------------- per-dst attention: 1 wave/node, 4 nodes/block, no LDS ----------------
__global__ __launch_bounds__(256) void attn_kernel(
    const bf16* __restrict__ Qb, const bf16* __restrict__ Kb, const bf16* __restrict__ Vb,
    const float* __restrict__ pos, const float* __restrict__ Wp1, const float* __restrict__ bp1,
    const int* __restrict__ rowptr, const int* __restrict__ srcs,
    float* __restrict__ acc1, bf16* __restrict__ acc2, float* __restrict__ sattn) {
  int n = blockIdx.x * 4 + (threadIdx.x >> 6);
  int lane = threadIdx.x & 63;
  int d = lane * 4;
  int e0 = min(max(rowptr[n], 0), NE);
  int e1 = min(max(rowptr[n + 1], e0), NE);
  float q[4];
  {
    bf16x4 qv = *(const bf16x4*)(Qb + (size_t)n * 256 + d);
    q[0] = (float)qv[0]; q[1] = (float)qv[1]; q[2] = (float)qv[2]; q[3] = (float)qv[3];
  }
  float px = pos[n * 3], py = pos[n * 3 + 1], pz = pos[n * 3 + 2];
  float w0[4], w1[4], w2[4], bp[4];
#pragma unroll
  for (int j = 0; j < 4; ++j) {
    w0[j] = Wp1[d + j];
    w1[j] = Wp1[256 + d + j];
    w2[j] = Wp1[512 + d + j];
    bp[j] = bp1[d + j];
  }
  float m = -INFINITY, denom = 0.0f;
  float aV[4] = {0, 0, 0, 0}, aP[4] = {0, 0, 0, 0};
  for (int base = e0; base < e1; base += 64) {
    int cnt = min(64, e1 - base);
    int srcReg = (base + lane < e1) ? srcs[base + lane] : 0;
    float alphaKeep = -INFINITY;  // lane i holds alpha of edge base+i
    // pass 1: alpha = dot(Q[n], K[src]) / 16 (whole wave per edge, coalesced row)
    for (int i = 0; i < cnt; ++i) {
      int s = __builtin_amdgcn_readlane(srcReg, i);  // uniform -> SGPR row base
      bf16x4 kv = *(const bf16x4*)(Kb + (size_t)s * 256 + d);
      float pd = q[0] * (float)kv[0] + q[1] * (float)kv[1] +
                 q[2] * (float)kv[2] + q[3] * (float)kv[3];
      pd = wave_sum(pd) * 0.0625f;
      alphaKeep = (lane == i) ? pd : alphaKeep;
    }
    // online softmax rescale
    float mc = wave_max(alphaKeep);
    float newm = fmaxf(m, mc);
    float scale = __expf(m - newm);  // 0 on first chunk (m = -inf)
    denom *= scale;
#pragma unroll
    for (int j = 0; j < 4; ++j) { aV[j] *= scale; aP[j] *= scale; }
    m = newm;
    // pass 2: accumulate wgt*V[src] and wgt*relu(rel_pos@Wp1+bp1)
    for (int i = 0; i < cnt; ++i) {
      float a = __int_as_float(__builtin_amdgcn_readlane(__float_as_int(alphaKeep), i));
      float wgt = __expf(a - m);
      denom += wgt;  // uniform across lanes
      int s = __builtin_amdgcn_readlane(srcReg, i);
      bf16x4 vv = *(const bf16x4*)(Vb + (size_t)s * 256 + d);
      float rx = pos[s * 3] - px, ry = pos[s * 3 + 1] - py, rz = pos[s * 3 + 2] - pz;
#pragma unroll
      for (int j = 0; j < 4; ++j) {
        float p1 = fmaf(rx, w0[j], fmaf(ry, w1[j], fmaf(rz, w2[j], bp[j])));
        p1 = fmaxf(p1, 0.0f);
        aV[j] = fmaf(wgt, (float)vv[j], aV[j]);
        aP[j] = fmaf(wgt, p1, aP[j]);
      }
    }
  }
  float r = 1.0f / (denom + 1e-16f);
  if (lane == 0) sattn[n] = denom * r;
#pragma unroll
  for (int j = 0; j < 4; ++j) {
    acc1[(size_t)n * 256 + d + j] = aV[j] * r;
    acc2[(size_t)n * 256 + d + j] = (bf16)(aP[j] * r);
  }
}

// ---------------- fused epilogue: residuals + two LayerNorms ----------------
__global__ __launch_bounds__(256) void final_kernel(
    const float* __restrict__ acc1, const float* __restrict__ tmp,
    const float* __restrict__ sattn, const float* __restrict__ bp2,
    const float* __restrict__ hf, const float* __restrict__ x,
    const float* __restrict__ g1, const float* __restrict__ b1n,
    const float* __restrict__ g2, const float* __restrict__ b2n,
    float* __restrict__ out) {
  int n = blockIdx.x * 4 + (threadIdx.x >> 6);
  int lane = threadIdx.x & 63;
  int d = lane * 4;
  size_t nd = (size_t)n * 256 + d;
  float s = sattn[n];
  float v[4];
#pragma unroll
  for (int j = 0; j < 4; ++j)
    v[j] = acc1[nd + j] + tmp[nd + j] + s * bp2[d + j] + hf[nd + j];
  float mu = wave_sum(v[0] + v[1] + v[2] + v[3]) * (1.0f / 256.0f);
  float ss = 0;
#pragma unroll
  for (int j = 0; j < 4; ++j) { float t = v[j] - mu; ss += t * t; }
  float rstd = rsqrtf(wave_sum(ss) * (1.0f / 256.0f) + 1e-5f);
  float u[4];
#pragma unroll
  for (int j = 0; j < 4; ++j)
    u[j] = (v[j] - mu) * rstd * g1[d + j] + b1n[d + j] + x[nd + j];
  float mu2 = wave_sum(u[0] + u[1] + u[2] + u[3]) * (1.0f / 256.0f);
  float ss2 = 0;
#pragma unroll
  for (int j = 0; j < 4; ++j) { float t = u[j] - mu2; ss2 += t * t; }
  float rstd2 = rsqrtf(wave_sum(ss2) * (1.0f / 256.0f) + 1e-5f);
#pragma unroll
  for (int j = 0; j < 4; ++j)
    out[nd + j] = (u[j] - mu2) * rstd2 * g2[d + j] + b2n[d + j];
}

extern "C" void kernel_launch(void* const* d_in, const int* in_sizes, int n_in,
                              void* d_out, int out_size, void* d_ws, size_t ws_size,
                              hipStream_t stream) {
  (void)in_sizes; (void)n_in; (void)out_size; (void)ws_size;
  const float* x   = (const float*)d_in[0];
  const int*   ei  = (const int*)d_in[1];
  const float* pos = (const float*)d_in[2];
  const float* Wm1 = (const float*)d_in[3];
  const float* bm1 = (const float*)d_in[4];
  const float* Wm2 = (const float*)d_in[5];
  const float* bm2 = (const float*)d_in[6];
  const float* Wq  = (const float*)d_in[7];
  const float* bq  = (const float*)d_in[8];
  const float* Wk  = (const float*)d_in[9];
  const float* bk  = (const float*)d_in[10];
  const float* Wv  = (const float*)d_in[11];
  const float* bv  = (const float*)d_in[12];
  const float* Wp1 = (const float*)d_in[13];
  const float* bp1 = (const float*)d_in[14];
  const float* Wp2 = (const float*)d_in[15];
  const float* bp2 = (const float*)d_in[16];
  const float* g1  = (const float*)d_in[17];
  const float* b1n = (const float*)d_in[18];
  const float* g2  = (const float*)d_in[19];
  const float* b2n = (const float*)d_in[20];

  const size_t ND = (size_t)NN * DD;
  char* p = (char*)d_ws;
  auto alloc = [&](size_t bytes) {
    char* r = p;
    p += (bytes + 255) & ~(size_t)255;
    return r;
  };
  bf16* btbase = (bf16*)alloc(6 * 65536 * sizeof(bf16));  // contiguous
  bf16* xb   = (bf16*)alloc(ND * 2);
  bf16* h1b  = (bf16*)alloc(ND * 2);
  bf16* hb   = (bf16*)alloc(ND * 2);
  float* hf  = (float*)alloc(ND * 4);
  bf16* Qb   = (bf16*)alloc(ND * 2);
  float* acc1 = (float*)alloc(ND * 4);
  bf16* acc2  = (bf16*)alloc(ND * 2);
  float* tmp  = (float*)alloc(ND * 4);
  float* sattn = (float*)alloc(NN * 4);
  int* deg    = (int*)alloc(NN * 4);
  int* rowptr = (int*)alloc((NN + 1) * 4);
  int* cursor = (int*)alloc(NN * 4);
  int* srcs   = (int*)alloc(NE * 4);
  int* eflag  = (int*)alloc(256);
  // safe aliases (xb dead after g1, h1b dead after g2)
  bf16* Kb = xb;
  bf16* Vb = h1b;

  detect_kernel<<<1, 64, 0, stream>>>(ei, eflag);
  hipMemsetAsync(deg, 0, NN * 4, stream);

  TW tw;
  tw.w[0] = Wm1; tw.w[1] = Wm2; tw.w[2] = Wq; tw.w[3] = Wk; tw.w[4] = Wv; tw.w[5] = Wp2;
  for (int i = 0; i < 6; ++i) tw.o[i] = btbase + i * 65536;
  transpose_all<<<6 * 64, 256, 0, stream>>>(tw);
  cvt_bf16<<<(int)(ND / 1024), 256, 0, stream>>>(x, xb, (int)ND);

  const int GX = (NN + 63) / 64;  // 157
  GArgs a1 = {{{bm1, nullptr, h1b}, {}, {}}};
  gemmw<1><<<dim3(GX, 2), 256, 0, stream>>>(xb, btbase + 0 * 65536, a1, NN);
  GArgs a2 = {{{bm2, hf, hb}, {}, {}}};
  gemmw<0><<<dim3(GX, 2), 256, 0, stream>>>(h1b, btbase + 1 * 65536, a2, NN);
  GArgs aqkv = {{{bq, nullptr, Qb}, {bk, nullptr, Kb}, {bv, nullptr, Vb}}};
  gemmw<0><<<dim3(GX, 6), 256, 0, stream>>>(hb, btbase + 2 * 65536, aqkv, NN);

  hist_kernel<<<(NE + 255) / 256, 256, 0, stream>>>(ei, eflag, deg);
  scan_kernel<<<1, 1024, 0, stream>>>(deg, rowptr, cursor, NN);
  scatter_kernel<<<(NE + 255) / 256, 256, 0, stream>>>(ei, eflag, cursor, srcs);

  attn_kernel<<<NN / 4, 256, 0, stream>>>(Qb, Kb, Vb, pos, Wp1, bp1, rowptr, srcs,
                                          acc1, acc2, sattn);
  GArgs ap2 = {{{nullptr, tmp, nullptr}, {}, {}}};
  gemmw<0><<<dim3(GX, 2), 256, 0, stream>>>(acc2, btbase + 5 * 65536, ap2, NN);

  final_kernel<<<NN / 4, 256, 0, stream>>>(acc1, tmp, sattn, bp2, hf, x, g1, b1n,
                                           g2, b2n, (float*)d_out);
}

// Round 6
// 240.433 us; speedup vs baseline: 1.1160x; 1.0903x over previous
//
#include <hip/hip_runtime.h>
#include <hip/hip_bf16.h>
#include <math.h>

// AGTBlock: x->MLP->h; Q,K,V=h@W*; edge attention grouped by dst with segment
// softmax; msg = attn*(V[src]+posMLP(pos[src]-pos[dst])); out = LN(LN(sum+h)+x).
// Restructure: Wp2 pulled out of edge sum (node GEMM on attn-weighted relu acts).
// Attn v3: 16-edge chunks; QK dots via MFMA (K-rows x Q-broadcast); single-pass
// softmax (no max-shift; alphas tiny, shift-invariant); unrolled masked V-accum
// for deep memory-level parallelism. 1 wave/node, 4 nodes/block, no LDS.

#define NN 10000
#define NE 320000
#define DD 256

typedef __bf16 bf16;
typedef __bf16 bf16x8 __attribute__((ext_vector_type(8)));
typedef __bf16 bf16x4 __attribute__((ext_vector_type(4)));
typedef float f32x4 __attribute__((ext_vector_type(4)));

__device__ __forceinline__ float wave_sum(float v) {
#pragma unroll
  for (int off = 32; off; off >>= 1) v += __shfl_xor(v, off, 64);
  return v;
}

// ---------------- edge dtype detect (int32 vs int64), wave-parallel ----------------
__global__ void detect_kernel(const int* __restrict__ ei, int* __restrict__ flag) {
  int lane = threadIdx.x;  // 64
  int nz = 0;
#pragma unroll
  for (int i = 0; i < 4; ++i)
    nz |= (ei[2 * (lane + 64 * i) + 1] != 0);
  unsigned long long b = __ballot(nz);
  if (lane == 0) *flag = (b == 0ull) ? 1 : 0;  // all-high-words-zero -> int64
}

__device__ __forceinline__ void load_edge(const int* __restrict__ ei, int is64,
                                          int e, int& s, int& dn) {
  if (is64) {
    const long long* e64 = (const long long*)ei;
    s = (int)e64[e];
    dn = (int)e64[NE + e];
  } else {
    s = ei[e];
    dn = ei[NE + e];
  }
  s = min(max(s, 0), NN - 1);
  dn = min(max(dn, 0), NN - 1);
}

// ---------------- prep: tiled weight transpose -> bf16, x -> bf16 ----------------
struct TW { const float* w[6]; bf16* o[6]; };

__global__ __launch_bounds__(256) void transpose_all(TW tw) {
  int t = blockIdx.x & 63;   // tile within matrix (8x8 grid of 32x32)
  int b = blockIdx.x >> 6;   // matrix 0..5
  int tr = (t >> 3) * 32;
  int tc = (t & 7) * 32;
  __shared__ float tile[32][33];
  int tx = threadIdx.x & 31, ty = threadIdx.x >> 5;  // 32 x 8
  const float* w = tw.w[b];
#pragma unroll
  for (int i = 0; i < 32; i += 8)
    tile[ty + i][tx] = w[(tr + ty + i) * 256 + tc + tx];
  __syncthreads();
  bf16* o = tw.o[b];
#pragma unroll
  for (int i = 0; i < 32; i += 8)
    o[(tc + ty + i) * 256 + tr + tx] = (bf16)tile[tx][ty + i];  // o[n][k]=w[k][n]
}

__global__ __launch_bounds__(256) void cvt_bf16(const float* __restrict__ x,
                                                bf16* __restrict__ o, int n) {
  int i = (blockIdx.x * 256 + threadIdx.x) * 4;
  if (i + 3 < n) {
    float4 v = *(const float4*)(x + i);
    bf16x4 b;
    b[0] = (bf16)v.x; b[1] = (bf16)v.y; b[2] = (bf16)v.z; b[3] = (bf16)v.w;
    *(bf16x4*)(o + i) = b;
  }
}

// ---------------- GEMM: C[M,256] = A[M,256] @ Bt[seg]^T + bias[seg] ----------------
struct GSeg { const float* bias; float* cf; bf16* cb; };
struct GArgs { GSeg s[3]; };

template <int RELU>
__global__ __launch_bounds__(256) void gemmw(
    const bf16* __restrict__ A, const bf16* __restrict__ Bt0, GArgs ga, int M) {
  int w = threadIdx.x >> 6, lane = threadIdx.x & 63;
  int lr = lane & 15, kh = lane >> 4;
  int row16 = (blockIdx.x * 4 + w) * 16;
  int seg = blockIdx.y >> 1;
  int colbase = (blockIdx.y & 1) * 128;
  GSeg gs = ga.s[seg];
  const bf16* Bt = Bt0 + seg * 65536;
  f32x4 acc[8] = {};
  int arow = row16 + lr;
  if (arow >= M) arow = M - 1;  // clamp; masked on store
  const bf16* Ap = A + (size_t)arow * 256 + kh * 8;
  const bf16* Bp = Bt + (size_t)(colbase + lr) * 256 + kh * 8;
#pragma unroll
  for (int kk = 0; kk < 8; ++kk) {
    bf16x8 af = *(const bf16x8*)(Ap + kk * 32);
#pragma unroll
    for (int nf = 0; nf < 8; ++nf) {
      bf16x8 bfr = *(const bf16x8*)(Bp + nf * 16 * 256 + kk * 32);
      acc[nf] = __builtin_amdgcn_mfma_f32_16x16x32_bf16(af, bfr, acc[nf], 0, 0, 0);
    }
  }
  int crow = row16 + kh * 4;  // C/D layout (m89): col = lane&15, row = kh*4 + j
#pragma unroll
  for (int nf = 0; nf < 8; ++nf) {
    int ccol = colbase + nf * 16 + lr;
    float bv = gs.bias ? gs.bias[ccol] : 0.0f;
#pragma unroll
    for (int j = 0; j < 4; ++j) {
      int r = crow + j;
      if (r < M) {
        float v = acc[nf][j] + bv;
        if (RELU) v = fmaxf(v, 0.0f);
        if (gs.cf) gs.cf[(size_t)r * 256 + ccol] = v;
        if (gs.cb) gs.cb[(size_t)r * 256 + ccol] = (bf16)v;
      }
    }
  }
}

// ---------------- CSR build by dst ----------------
__global__ void hist_kernel(const int* __restrict__ ei, const int* __restrict__ flag,
                            int* __restrict__ deg) {
  int e = blockIdx.x * 256 + threadIdx.x;
  if (e < NE) {
    int s, dn;
    load_edge(ei, *flag, e, s, dn);
    atomicAdd(&deg[dn], 1);
  }
}

__global__ __launch_bounds__(1024) void scan_kernel(
    const int* __restrict__ deg, int* __restrict__ rowptr,
    int* __restrict__ cursor, int n) {
  __shared__ int wsum[16];
  __shared__ int carry_s;
  int t = threadIdx.x, wid = t >> 6, lane = t & 63;
  if (t == 0) { carry_s = 0; rowptr[0] = 0; }
  __syncthreads();
  for (int base = 0; base < n; base += 1024) {
    int idx = base + t;
    int v = (idx < n) ? deg[idx] : 0;
    int x = v;
#pragma unroll
    for (int off = 1; off < 64; off <<= 1) {
      int y = __shfl_up(x, off, 64);
      if (lane >= off) x += y;
    }
    if (lane == 63) wsum[wid] = x;
    __syncthreads();
    if (wid == 0) {
      int s = (lane < 16) ? wsum[lane] : 0;
#pragma unroll
      for (int off = 1; off < 16; off <<= 1) {
        int y = __shfl_up(s, off, 64);
        if (lane >= off) s += y;
      }
      if (lane < 16) wsum[lane] = s;
    }
    __syncthreads();
    int waveoff = (wid > 0) ? wsum[wid - 1] : 0;
    int carry = carry_s;
    int incl = carry + waveoff + x;
    if (idx < n) {
      rowptr[idx + 1] = incl;
      cursor[idx] = incl - v;
    }
    __syncthreads();
    if (t == 1023) carry_s = incl;
    __syncthreads();
  }
}

__global__ void scatter_kernel(const int* __restrict__ ei, const int* __restrict__ flag,
                               int* __restrict__ cursor, int* __restrict__ srcs) {
  int e = blockIdx.x * 256 + threadIdx.x;
  if (e < NE) {
    int s, dn;
    load_edge(ei, *flag, e, s, dn);
    int slot = atomicAdd(&cursor[dn], 1);
    if (slot >= 0 && slot < NE) srcs[slot] = s;
  }
}

// ---------------- per-dst attention v3: MFMA alphas, single pass ----------------
__global__ __launch_bounds__(256) void attn_kernel(
    const bf16* __restrict__ Qb, const bf16* __restrict__ Kb, const bf16* __restrict__ Vb,
    const float* __restrict__ pos, const float* __restrict__ Wp1, const float* __restrict__ bp1,
    const int* __restrict__ rowptr, const int* __restrict__ srcs,
    float* __restrict__ acc1, bf16* __restrict__ acc2, float* __restrict__ sattn) {
  int n = blockIdx.x * 4 + (threadIdx.x >> 6);
  int lane = threadIdx.x & 63;
  int lr = lane & 15, kh = lane >> 4;
  int d = lane * 4;
  int e0 = min(max(rowptr[n], 0), NE);
  int e1 = min(max(rowptr[n + 1], e0), NE);
  // Q fragments: B-operand broadcast over all 16 cols (lane supplies k-chunk kh*8)
  bf16x8 qf[8];
#pragma unroll
  for (int m = 0; m < 8; ++m)
    qf[m] = *(const bf16x8*)(Qb + (size_t)n * 256 + m * 32 + kh * 8);
  float px = pos[n * 3], py = pos[n * 3 + 1], pz = pos[n * 3 + 2];
  float w0[4], w1[4], w2[4], bp[4];
#pragma unroll
  for (int j = 0; j < 4; ++j) {
    w0[j] = Wp1[d + j];
    w1[j] = Wp1[256 + d + j];
    w2[j] = Wp1[512 + d + j];
    bp[j] = bp1[d + j];
  }
  float aV[4] = {0, 0, 0, 0}, aP[4] = {0, 0, 0, 0};
  float dpart = 0.0f;
  for (int base = e0; base < e1; base += 16) {
    // src of edge (base + lr) in lane lr (lanes 16.. replicate)
    int sv = srcs[min(base + lr, e1 - 1)];
    // alphas for 16 edges: A = gathered K rows (row = lane&15), B = Q broadcast
    f32x4 al = {0.0f, 0.0f, 0.0f, 0.0f};
#pragma unroll
    for (int m = 0; m < 8; ++m) {
      bf16x8 kf = *(const bf16x8*)(Kb + (size_t)sv * 256 + m * 32 + kh * 8);
      al = __builtin_amdgcn_mfma_f32_16x16x32_bf16(kf, qf[m], al, 0, 0, 0);
    }
    // lane holds alpha of edge base + kh*4 + j in al[j] (replicated over 16 cols)
    float wg[4];
#pragma unroll
    for (int j = 0; j < 4; ++j) {
      int e = base + kh * 4 + j;
      wg[j] = (e < e1) ? __expf(al[j] * 0.0625f) : 0.0f;  // alpha/sqrt(256)
      dpart += wg[j];
    }
    // accumulate wgt*V[src] and wgt*relu(rel_pos@Wp1+bp1); wgt=0 masks padding
#pragma unroll
    for (int ii = 0; ii < 4; ++ii) {
      if (base + ii * 4 < e1) {
#pragma unroll
        for (int j = 0; j < 4; ++j) {
          float we = __int_as_float(
              __builtin_amdgcn_readlane(__float_as_int(wg[j]), ii * 16));
          int se = __builtin_amdgcn_readlane(sv, ii * 4 + j);
          bf16x4 vv = *(const bf16x4*)(Vb + (size_t)se * 256 + d);
          float rx = pos[se * 3] - px, ry = pos[se * 3 + 1] - py,
                rz = pos[se * 3 + 2] - pz;
#pragma unroll
          for (int jj = 0; jj < 4; ++jj) {
            float p1 = fmaf(rx, w0[jj], fmaf(ry, w1[jj], fmaf(rz, w2[jj], bp[jj])));
            p1 = fmaxf(p1, 0.0f);
            aV[jj] = fmaf(we, (float)vv[jj], aV[jj]);
            aP[jj] = fmaf(we, p1, aP[jj]);
          }
        }
      }
    }
  }
  float denom = wave_sum(dpart) * (1.0f / 16.0f);  // each edge replicated x16
  float r = 1.0f / (denom + 1e-16f);
  if (lane == 0) sattn[n] = denom * r;
#pragma unroll
  for (int j = 0; j < 4; ++j) {
    acc1[(size_t)n * 256 + d + j] = aV[j] * r;
    acc2[(size_t)n * 256 + d + j] = (bf16)(aP[j] * r);
  }
}

// ---------------- fused epilogue: residuals + two LayerNorms ----------------
__global__ __launch_bounds__(256) void final_kernel(
    const float* __restrict__ acc1, const float* __restrict__ tmp,
    const float* __restrict__ sattn, const float* __restrict__ bp2,
    const float* __restrict__ hf, const float* __restrict__ x,
    const float* __restrict__ g1, const float* __restrict__ b1n,
    const float* __restrict__ g2, const float* __restrict__ b2n,
    float* __restrict__ out) {
  int n = blockIdx.x * 4 + (threadIdx.x >> 6);
  int lane = threadIdx.x & 63;
  int d = lane * 4;
  size_t nd = (size_t)n * 256 + d;
  float s = sattn[n];
  float v[4];
#pragma unroll
  for (int j = 0; j < 4; ++j)
    v[j] = acc1[nd + j] + tmp[nd + j] + s * bp2[d + j] + hf[nd + j];
  float mu = wave_sum(v[0] + v[1] + v[2] + v[3]) * (1.0f / 256.0f);
  float ss = 0;
#pragma unroll
  for (int j = 0; j < 4; ++j) { float t = v[j] - mu; ss += t * t; }
  float rstd = rsqrtf(wave_sum(ss) * (1.0f / 256.0f) + 1e-5f);
  float u[4];
#pragma unroll
  for (int j = 0; j < 4; ++j)
    u[j] = (v[j] - mu) * rstd * g1[d + j] + b1n[d + j] + x[nd + j];
  float mu2 = wave_sum(u[0] + u[1] + u[2] + u[3]) * (1.0f / 256.0f);
  float ss2 = 0;
#pragma unroll
  for (int j = 0; j < 4; ++j) { float t = u[j] - mu2; ss2 += t * t; }
  float rstd2 = rsqrtf(wave_sum(ss2) * (1.0f / 256.0f) + 1e-5f);
#pragma unroll
  for (int j = 0; j < 4; ++j)
    out[nd + j] = (u[j] - mu2) * rstd2 * g2[d + j] + b2n[d + j];
}

extern "C" void kernel_launch(void* const* d_in, const int* in_sizes, int n_in,
                              void* d_out, int out_size, void* d_ws, size_t ws_size,
                              hipStream_t stream) {
  (void)in_sizes; (void)n_in; (void)out_size; (void)ws_size;
  const float* x   = (const float*)d_in[0];
  const int*   ei  = (const int*)d_in[1];
  const float* pos = (const float*)d_in[2];
  const float* Wm1 = (const float*)d_in[3];
  const float* bm1 = (const float*)d_in[4];
  const float* Wm2 = (const float*)d_in[5];
  const float* bm2 = (const float*)d_in[6];
  const float* Wq  = (const float*)d_in[7];
  const float* bq  = (const float*)d_in[8];
  const float* Wk  = (const float*)d_in[9];
  const float* bk  = (const float*)d_in[10];
  const float* Wv  = (const float*)d_in[11];
  const float* bv  = (const float*)d_in[12];
  const float* Wp1 = (const float*)d_in[13];
  const float* bp1 = (const float*)d_in[14];
  const float* Wp2 = (const float*)d_in[15];
  const float* bp2 = (const float*)d_in[16];
  const float* g1  = (const float*)d_in[17];
  const float* b1n = (const float*)d_in[18];
  const float* g2  = (const float*)d_in[19];
  const float* b2n = (const float*)d_in[20];

  const size_t ND = (size_t)NN * DD;
  char* p = (char*)d_ws;
  auto alloc = [&](size_t bytes) {
    char* r = p;
    p += (bytes + 255) & ~(size_t)255;
    return r;
  };
  bf16* btbase = (bf16*)alloc(6 * 65536 * sizeof(bf16));
  bf16* xb   = (bf16*)alloc(ND * 2);
  bf16* h1b  = (bf16*)alloc(ND * 2);
  bf16* hb   = (bf16*)alloc(ND * 2);
  float* hf  = (float*)alloc(ND * 4);
  bf16* Qb   = (bf16*)alloc(ND * 2);
  float* acc1 = (float*)alloc(ND * 4);
  bf16* acc2  = (bf16*)alloc(ND * 2);
  float* tmp  = (float*)alloc(ND * 4);
  float* sattn = (float*)alloc(NN * 4);
  int* deg    = (int*)alloc(NN * 4);
  int* rowptr = (int*)alloc((NN + 1) * 4);
  int* cursor = (int*)alloc(NN * 4);
  int* srcs   = (int*)alloc(NE * 4);
  int* eflag  = (int*)alloc(256);
  bf16* Kb = xb;   // xb dead after MLP1
  bf16* Vb = h1b;  // h1b dead after MLP2

  detect_kernel<<<1, 64, 0, stream>>>(ei, eflag);
  hipMemsetAsync(deg, 0, NN * 4, stream);

  TW tw;
  tw.w[0] = Wm1; tw.w[1] = Wm2; tw.w[2] = Wq; tw.w[3] = Wk; tw.w[4] = Wv; tw.w[5] = Wp2;
  for (int i = 0; i < 6; ++i) tw.o[i] = btbase + i * 65536;
  transpose_all<<<6 * 64, 256, 0, stream>>>(tw);
  cvt_bf16<<<(int)(ND / 1024), 256, 0, stream>>>(x, xb, (int)ND);

  const int GX = (NN + 63) / 64;  // 157
  GArgs a1 = {{{bm1, nullptr, h1b}, {}, {}}};
  gemmw<1><<<dim3(GX, 2), 256, 0, stream>>>(xb, btbase + 0 * 65536, a1, NN);
  GArgs a2 = {{{bm2, hf, hb}, {}, {}}};
  gemmw<0><<<dim3(GX, 2), 256, 0, stream>>>(h1b, btbase + 1 * 65536, a2, NN);
  GArgs aqkv = {{{bq, nullptr, Qb}, {bk, nullptr, Kb}, {bv, nullptr, Vb}}};
  gemmw<0><<<dim3(GX, 6), 256, 0, stream>>>(hb, btbase + 2 * 65536, aqkv, NN);

  hist_kernel<<<(NE + 255) / 256, 256, 0, stream>>>(ei, eflag, deg);
  scan_kernel<<<1, 1024, 0, stream>>>(deg, rowptr, cursor, NN);
  scatter_kernel<<<(NE + 255) / 256, 256, 0, stream>>>(ei, eflag, cursor, srcs);

  attn_kernel<<<NN / 4, 256, 0, stream>>>(Qb, Kb, Vb, pos, Wp1, bp1, rowptr, srcs,
                                          acc1, acc2, sattn);
  GArgs ap2 = {{{nullptr, tmp, nullptr}, {}, {}}};
  gemmw<0><<<dim3(GX, 2), 256, 0, stream>>>(acc2, btbase + 5 * 65536, ap2, NN);

  final_kernel<<<NN / 4, 256, 0, stream>>>(acc1, tmp, sattn, bp2, hf, x, g1, b1n,
                                           g2, b2n, (float*)d_out);
}

// Round 7
// 224.428 us; speedup vs baseline: 1.1956x; 1.0713x over previous
//
#include <hip/hip_runtime.h>
#include <hip/hip_bf16.h>
#include <math.h>

// AGTBlock: x->MLP->h; Q,K,V=h@W*; edge attention grouped by dst with segment
// softmax; msg = attn*(V[src]+posMLP(pos[src]-pos[dst])); out = LN(LN(sum+h)+x).
// Restructure: Wp2 pulled out of edge sum; P2-GEMM fused into final (MFMA +
// in-register double LayerNorm). Attn: 16-edge chunks, MFMA QK dots, single-pass
// exp (no max shift; alphas tiny). 9 launches total.

#define NN 10000
#define NE 320000
#define DD 256

typedef __bf16 bf16;
typedef __bf16 bf16x8 __attribute__((ext_vector_type(8)));
typedef __bf16 bf16x4 __attribute__((ext_vector_type(4)));
typedef float f32x4 __attribute__((ext_vector_type(4)));

__device__ __forceinline__ float wave_sum(float v) {
#pragma unroll
  for (int off = 32; off; off >>= 1) v += __shfl_xor(v, off, 64);
  return v;
}

// is64 inline detect: high words of first 4 int64 edges are 0 (values < 2^31).
// If int32, these are src[1],src[3],src[5],src[7] — all-zero prob ~1e-16.
__device__ __forceinline__ int detect64(const int* __restrict__ ei) {
  return (ei[1] | ei[3] | ei[5] | ei[7]) == 0;
}

__device__ __forceinline__ void load_edge(const int* __restrict__ ei, int is64,
                                          int e, int& s, int& dn) {
  if (is64) {
    const long long* e64 = (const long long*)ei;
    s = (int)e64[e];
    dn = (int)e64[NE + e];
  } else {
    s = ei[e];
    dn = ei[NE + e];
  }
  s = min(max(s, 0), NN - 1);
  dn = min(max(dn, 0), NN - 1);
}

// ---------------- prep: transpose(6) + cvt x->bf16 + zero deg, one launch ----------------
struct PrepArgs { const float* w[6]; bf16* o[6]; const float* x; bf16* xb; int* deg; };

__global__ __launch_bounds__(256) void prep_kernel(PrepArgs pa) {
  int b = blockIdx.x;
  if (b < 384) {  // 6 matrices x 64 tiles of 32x32: o[n][k] = w[k][n], f32->bf16
    int t = b & 63, mat = b >> 6;
    int tr = (t >> 3) * 32, tc = (t & 7) * 32;
    __shared__ float tile[32][33];
    int tx = threadIdx.x & 31, ty = threadIdx.x >> 5;
    const float* w = pa.w[mat];
#pragma unroll
    for (int i = 0; i < 32; i += 8)
      tile[ty + i][tx] = w[(tr + ty + i) * 256 + tc + tx];
    __syncthreads();
    bf16* o = pa.o[mat];
#pragma unroll
    for (int i = 0; i < 32; i += 8)
      o[(tc + ty + i) * 256 + tr + tx] = (bf16)tile[tx][ty + i];
  } else if (b < 384 + 2500) {  // cvt 2.56M f32 -> bf16, 1024/block
    int i = ((b - 384) * 256 + threadIdx.x) * 4;
    float4 v = *(const float4*)(pa.x + i);
    bf16x4 o;
    o[0] = (bf16)v.x; o[1] = (bf16)v.y; o[2] = (bf16)v.z; o[3] = (bf16)v.w;
    *(bf16x4*)(pa.xb + i) = o;
  } else {  // zero deg
    int i = (b - 2884) * 256 + threadIdx.x;
    if (i < NN) pa.deg[i] = 0;
  }
}

// ---------------- GEMM: C[M,256] = A[M,256] @ Bt[seg]^T + bias[seg] ----------------
struct GSeg { const float* bias; float* cf; bf16* cb; };
struct GArgs { GSeg s[3]; };

template <int RELU>
__global__ __launch_bounds__(256) void gemmw(
    const bf16* __restrict__ A, const bf16* __restrict__ Bt0, GArgs ga, int M) {
  int w = threadIdx.x >> 6, lane = threadIdx.x & 63;
  int lr = lane & 15, kh = lane >> 4;
  int row16 = (blockIdx.x * 4 + w) * 16;
  int seg = blockIdx.y >> 1;
  int colbase = (blockIdx.y & 1) * 128;
  GSeg gs = ga.s[seg];
  const bf16* Bt = Bt0 + seg * 65536;
  f32x4 acc[8] = {};
  int arow = row16 + lr;
  if (arow >= M) arow = M - 1;  // clamp; masked on store
  const bf16* Ap = A + (size_t)arow * 256 + kh * 8;
  const bf16* Bp = Bt + (size_t)(colbase + lr) * 256 + kh * 8;
#pragma unroll
  for (int kk = 0; kk < 8; ++kk) {
    bf16x8 af = *(const bf16x8*)(Ap + kk * 32);
#pragma unroll
    for (int nf = 0; nf < 8; ++nf) {
      bf16x8 bfr = *(const bf16x8*)(Bp + nf * 16 * 256 + kk * 32);
      acc[nf] = __builtin_amdgcn_mfma_f32_16x16x32_bf16(af, bfr, acc[nf], 0, 0, 0);
    }
  }
  int crow = row16 + kh * 4;  // C/D: col = lane&15, row = kh*4 + j (m89)
#pragma unroll
  for (int nf = 0; nf < 8; ++nf) {
    int ccol = colbase + nf * 16 + lr;
    float bv = gs.bias ? gs.bias[ccol] : 0.0f;
#pragma unroll
    for (int j = 0; j < 4; ++j) {
      int r = crow + j;
      if (r < M) {
        float v = acc[nf][j] + bv;
        if (RELU) v = fmaxf(v, 0.0f);
        if (gs.cf) gs.cf[(size_t)r * 256 + ccol] = v;
        if (gs.cb) gs.cb[(size_t)r * 256 + ccol] = (bf16)v;
      }
    }
  }
}

// ---------------- CSR build by dst ----------------
__global__ void hist_kernel(const int* __restrict__ ei, int* __restrict__ deg) {
  int is64 = detect64(ei);
  int e = blockIdx.x * 256 + threadIdx.x;
  if (e < NE) {
    int s, dn;
    load_edge(ei, is64, e, s, dn);
    atomicAdd(&deg[dn], 1);
  }
}

// one-pass scan: 10 elems/thread serial + block shuffle scan (3 barriers).
__global__ __launch_bounds__(1024) void scan_kernel(
    const int* __restrict__ deg, int* __restrict__ rowptr,
    int* __restrict__ cursor) {
  __shared__ int wsum[16];
  int t = threadIdx.x, wid = t >> 6, lane = t & 63;
  int base = t * 10;
  int v[10];
  int s = 0;
#pragma unroll
  for (int i = 0; i < 10; ++i) {
    int idx = base + i;
    v[i] = (idx < NN) ? deg[idx] : 0;
    s += v[i];
  }
  int x = s;
#pragma unroll
  for (int off = 1; off < 64; off <<= 1) {
    int y = __shfl_up(x, off, 64);
    if (lane >= off) x += y;
  }
  if (lane == 63) wsum[wid] = x;
  __syncthreads();
  if (wid == 0) {
    int ws = (lane < 16) ? wsum[lane] : 0;
#pragma unroll
    for (int off = 1; off < 16; off <<= 1) {
      int y = __shfl_up(ws, off, 64);
      if (lane >= off) ws += y;
    }
    if (lane < 16) wsum[lane] = ws;
  }
  __syncthreads();
  int run = ((wid > 0) ? wsum[wid - 1] : 0) + x - s;  // exclusive prefix
#pragma unroll
  for (int i = 0; i < 10; ++i) {
    int idx = base + i;
    if (idx < NN) {
      cursor[idx] = run;
      run += v[i];
      rowptr[idx + 1] = run;
    }
  }
  if (t == 0) rowptr[0] = 0;
}

__global__ void scatter_kernel(const int* __restrict__ ei,
                               int* __restrict__ cursor, int* __restrict__ srcs) {
  int is64 = detect64(ei);
  int e = blockIdx.x * 256 + threadIdx.x;
  if (e < NE) {
    int s, dn;
    load_edge(ei, is64, e, s, dn);
    int slot = atomicAdd(&cursor[dn], 1);
    if (slot >= 0 && slot < NE) srcs[slot] = s;
  }
}

// ---------------- per-dst attention: MFMA alphas, single pass ----------------
__global__ __launch_bounds__(256) void attn_kernel(
    const bf16* __restrict__ Qb, const bf16* __restrict__ Kb, const bf16* __restrict__ Vb,
    const float* __restrict__ pos, const float* __restrict__ Wp1, const float* __restrict__ bp1,
    const int* __restrict__ rowptr, const int* __restrict__ srcs,
    float* __restrict__ acc1, bf16* __restrict__ acc2, float* __restrict__ sattn) {
  int n = blockIdx.x * 4 + (threadIdx.x >> 6);
  int lane = threadIdx.x & 63;
  int lr = lane & 15, kh = lane >> 4;
  int d = lane * 4;
  int e0 = min(max(rowptr[n], 0), NE);
  int e1 = min(max(rowptr[n + 1], e0), NE);
  bf16x8 qf[8];
#pragma unroll
  for (int m = 0; m < 8; ++m)
    qf[m] = *(const bf16x8*)(Qb + (size_t)n * 256 + m * 32 + kh * 8);
  float px = pos[n * 3], py = pos[n * 3 + 1], pz = pos[n * 3 + 2];
  float w0[4], w1[4], w2[4], bp[4];
#pragma unroll
  for (int j = 0; j < 4; ++j) {
    w0[j] = Wp1[d + j];
    w1[j] = Wp1[256 + d + j];
    w2[j] = Wp1[512 + d + j];
    bp[j] = bp1[d + j];
  }
  float aV[4] = {0, 0, 0, 0}, aP[4] = {0, 0, 0, 0};
  float dpart = 0.0f;
  for (int base = e0; base < e1; base += 16) {
    int sv = srcs[min(base + lr, e1 - 1)];
    f32x4 al = {0.0f, 0.0f, 0.0f, 0.0f};
#pragma unroll
    for (int m = 0; m < 8; ++m) {
      bf16x8 kf = *(const bf16x8*)(Kb + (size_t)sv * 256 + m * 32 + kh * 8);
      al = __builtin_amdgcn_mfma_f32_16x16x32_bf16(kf, qf[m], al, 0, 0, 0);
    }
    float wg[4];
#pragma unroll
    for (int j = 0; j < 4; ++j) {
      int e = base + kh * 4 + j;
      wg[j] = (e < e1) ? __expf(al[j] * 0.0625f) : 0.0f;  // alpha/sqrt(256)
      dpart += wg[j];
    }
#pragma unroll
    for (int ii = 0; ii < 4; ++ii) {
      if (base + ii * 4 < e1) {
#pragma unroll
        for (int j = 0; j < 4; ++j) {
          float we = __int_as_float(
              __builtin_amdgcn_readlane(__float_as_int(wg[j]), ii * 16));
          int se = __builtin_amdgcn_readlane(sv, ii * 4 + j);
          bf16x4 vv = *(const bf16x4*)(Vb + (size_t)se * 256 + d);
          float rx = pos[se * 3] - px, ry = pos[se * 3 + 1] - py,
                rz = pos[se * 3 + 2] - pz;
#pragma unroll
          for (int jj = 0; jj < 4; ++jj) {
            float p1 = fmaf(rx, w0[jj], fmaf(ry, w1[jj], fmaf(rz, w2[jj], bp[jj])));
            p1 = fmaxf(p1, 0.0f);
            aV[jj] = fmaf(we, (float)vv[jj], aV[jj]);
            aP[jj] = fmaf(we, p1, aP[jj]);
          }
        }
      }
    }
  }
  float denom = wave_sum(dpart) * (1.0f / 16.0f);  // each edge replicated x16
  float r = 1.0f / (denom + 1e-16f);
  if (lane == 0) sattn[n] = denom * r;
#pragma unroll
  for (int j = 0; j < 4; ++j) {
    acc1[(size_t)n * 256 + d + j] = aV[j] * r;
    acc2[(size_t)n * 256 + d + j] = (bf16)(aP[j] * r);
  }
}

// ---------------- final: tmp = acc2@Wp2 (MFMA) + residuals + 2x LayerNorm ----------------
// Wave handles 16 nodes x 256 cols. C/D layout: lane(lr,kh) holds rows kh*4+j,
// cols nf*16+lr. LN reduces over the 16-lane lr-group (shfl_xor 1,2,4,8).
__global__ __launch_bounds__(256) void final_kernel(
    const bf16* __restrict__ acc2, const bf16* __restrict__ Bt5,
    const float* __restrict__ acc1, const float* __restrict__ sattn,
    const float* __restrict__ bp2, const float* __restrict__ hf,
    const float* __restrict__ x, const float* __restrict__ g1,
    const float* __restrict__ b1n, const float* __restrict__ g2,
    const float* __restrict__ b2n, float* __restrict__ out) {
  int w = threadIdx.x >> 6, lane = threadIdx.x & 63;
  int lr = lane & 15, kh = lane >> 4;
  int row16 = (blockIdx.x * 4 + w) * 16;
  int arow = min(row16 + lr, NN - 1);
  const bf16* Ap = acc2 + (size_t)arow * 256 + kh * 8;
  f32x4 acc[16] = {};
#pragma unroll
  for (int kk = 0; kk < 8; ++kk) {
    bf16x8 af = *(const bf16x8*)(Ap + kk * 32);
#pragma unroll
    for (int nf = 0; nf < 16; ++nf) {
      bf16x8 bfr = *(const bf16x8*)(Bt5 + (size_t)(nf * 16 + lr) * 256 + kh * 8 + kk * 32);
      acc[nf] = __builtin_amdgcn_mfma_f32_16x16x32_bf16(af, bfr, acc[nf], 0, 0, 0);
    }
  }
  int rows[4];
  float sr[4];
#pragma unroll
  for (int j = 0; j < 4; ++j) {
    rows[j] = min(row16 + kh * 4 + j, NN - 1);
    sr[j] = sattn[rows[j]];
  }
  // phase A: v = tmp + acc1 + s*bp2 + hf ; row mean/var
  float mu[4], rstd[4];
#pragma unroll
  for (int j = 0; j < 4; ++j) {
    float rs = 0;
#pragma unroll
    for (int nf = 0; nf < 16; ++nf) {
      int c = nf * 16 + lr;
      size_t idx = (size_t)rows[j] * 256 + c;
      float v = acc[nf][j] + acc1[idx] + sr[j] * bp2[c] + hf[idx];
      acc[nf][j] = v;
      rs += v;
    }
#pragma unroll
    for (int off = 1; off < 16; off <<= 1) rs += __shfl_xor(rs, off, 64);
    mu[j] = rs * (1.0f / 256.0f);
    float ss = 0;
#pragma unroll
    for (int nf = 0; nf < 16; ++nf) {
      float t = acc[nf][j] - mu[j];
      ss += t * t;
    }
#pragma unroll
    for (int off = 1; off < 16; off <<= 1) ss += __shfl_xor(ss, off, 64);
    rstd[j] = rsqrtf(ss * (1.0f / 256.0f) + 1e-5f);
  }
  // phase B: u = LN1*g1+b1n + x ; second row mean/var
#pragma unroll
  for (int j = 0; j < 4; ++j) {
    float rs = 0;
#pragma unroll
    for (int nf = 0; nf < 16; ++nf) {
      int c = nf * 16 + lr;
      float u = (acc[nf][j] - mu[j]) * rstd[j] * g1[c] + b1n[c] +
                x[(size_t)rows[j] * 256 + c];
      acc[nf][j] = u;
      rs += u;
    }
#pragma unroll
    for (int off = 1; off < 16; off <<= 1) rs += __shfl_xor(rs, off, 64);
    mu[j] = rs * (1.0f / 256.0f);
    float ss = 0;
#pragma unroll
    for (int nf = 0; nf < 16; ++nf) {
      float t = acc[nf][j] - mu[j];
      ss += t * t;
    }
#pragma unroll
    for (int off = 1; off < 16; off <<= 1) ss += __shfl_xor(ss, off, 64);
    rstd[j] = rsqrtf(ss * (1.0f / 256.0f) + 1e-5f);
  }
  // phase C: out = LN2*g2 + b2n
#pragma unroll
  for (int j = 0; j < 4; ++j) {
    int r = row16 + kh * 4 + j;
    if (r < NN) {
#pragma unroll
      for (int nf = 0; nf < 16; ++nf) {
        int c = nf * 16 + lr;
        out[(size_t)r * 256 + c] =
            (acc[nf][j] - mu[j]) * rstd[j] * g2[c] + b2n[c];
      }
    }
  }
}

extern "C" void kernel_launch(void* const* d_in, const int* in_sizes, int n_in,
                              void* d_out, int out_size, void* d_ws, size_t ws_size,
                              hipStream_t stream) {
  (void)in_sizes; (void)n_in; (void)out_size; (void)ws_size;
  const float* x   = (const float*)d_in[0];
  const int*   ei  = (const int*)d_in[1];
  const float* pos = (const float*)d_in[2];
  const float* Wm1 = (const float*)d_in[3];
  const float* bm1 = (const float*)d_in[4];
  const float* Wm2 = (const float*)d_in[5];
  const float* bm2 = (const float*)d_in[6];
  const float* Wq  = (const float*)d_in[7];
  const float* bq  = (const float*)d_in[8];
  const float* Wk  = (const float*)d_in[9];
  const float* bk  = (const float*)d_in[10];
  const float* Wv  = (const float*)d_in[11];
  const float* bv  = (const float*)d_in[12];
  const float* Wp1 = (const float*)d_in[13];
  const float* bp1 = (const float*)d_in[14];
  const float* Wp2 = (const float*)d_in[15];
  const float* bp2 = (const float*)d_in[16];
  const float* g1  = (const float*)d_in[17];
  const float* b1n = (const float*)d_in[18];
  const float* g2  = (const float*)d_in[19];
  const float* b2n = (const float*)d_in[20];

  const size_t ND = (size_t)NN * DD;
  char* p = (char*)d_ws;
  auto alloc = [&](size_t bytes) {
    char* r = p;
    p += (bytes + 255) & ~(size_t)255;
    return r;
  };
  bf16* btbase = (bf16*)alloc(6 * 65536 * sizeof(bf16));
  bf16* xb   = (bf16*)alloc(ND * 2);
  bf16* h1b  = (bf16*)alloc(ND * 2);
  bf16* hb   = (bf16*)alloc(ND * 2);
  float* hf  = (float*)alloc(ND * 4);
  bf16* Qb   = (bf16*)alloc(ND * 2);
  float* acc1 = (float*)alloc(ND * 4);
  bf16* acc2  = (bf16*)alloc(ND * 2);
  float* sattn = (float*)alloc(NN * 4);
  int* deg    = (int*)alloc(NN * 4);
  int* rowptr = (int*)alloc((NN + 1) * 4);
  int* cursor = (int*)alloc(NN * 4);
  int* srcs   = (int*)alloc(NE * 4);
  bf16* Kb = xb;   // xb dead after MLP1
  bf16* Vb = h1b;  // h1b dead after MLP2

  PrepArgs pa;
  pa.w[0] = Wm1; pa.w[1] = Wm2; pa.w[2] = Wq; pa.w[3] = Wk; pa.w[4] = Wv; pa.w[5] = Wp2;
  for (int i = 0; i < 6; ++i) pa.o[i] = btbase + i * 65536;
  pa.x = x; pa.xb = xb; pa.deg = deg;
  prep_kernel<<<2924, 256, 0, stream>>>(pa);

  hist_kernel<<<(NE + 255) / 256, 256, 0, stream>>>(ei, deg);
  scan_kernel<<<1, 1024, 0, stream>>>(deg, rowptr, cursor);
  scatter_kernel<<<(NE + 255) / 256, 256, 0, stream>>>(ei, cursor, srcs);

  const int GX = (NN + 63) / 64;  // 157
  GArgs a1 = {{{bm1, nullptr, h1b}, {}, {}}};
  gemmw<1><<<dim3(GX, 2), 256, 0, stream>>>(xb, btbase + 0 * 65536, a1, NN);
  GArgs a2 = {{{bm2, hf, hb}, {}, {}}};
  gemmw<0><<<dim3(GX, 2), 256, 0, stream>>>(h1b, btbase + 1 * 65536, a2, NN);
  GArgs aqkv = {{{bq, nullptr, Qb}, {bk, nullptr, Kb}, {bv, nullptr, Vb}}};
  gemmw<0><<<dim3(GX, 6), 256, 0, stream>>>(hb, btbase + 2 * 65536, aqkv, NN);

  attn_kernel<<<NN / 4, 256, 0, stream>>>(Qb, Kb, Vb, pos, Wp1, bp1, rowptr, srcs,
                                          acc1, acc2, sattn);

  final_kernel<<<GX, 256, 0, stream>>>(acc2, btbase + 5 * 65536, acc1, sattn, bp2,
                                       hf, x, g1, b1n, g2, b2n, (float*)d_out);
}